// Round 5
// baseline (1975.786 us; speedup 1.0000x reference)
//
#include <hip/hip_runtime.h>

#define T_STEPS 256
#define H1 5
#define H2 100
#define NS 2          // batch streams per wave
#define KE 108        // extended state: 100 h2 + 5 h1 + 3 zero pad
#define KROW 112      // LDS row stride (float4 aligned)
#define NK4 27        // KE/4 float4 groups per row

typedef float f32x2 __attribute__((ext_vector_type(2)));

// tanh(x) = 1 - 2/(exp(2x)+1); saturates correctly for |x| large.
__device__ __forceinline__ float fast_tanh(float v) {
    float e = __expf(2.0f * v);
    return 1.0f - 2.0f * __builtin_amdgcn_rcpf(e + 1.0f);
}

// ONE WAVE PER BLOCK (64 threads) — no __syncthreads anywhere.
// Lane j owns rows j and j+64 of the extended weight matrix
//   [Whh2 | Wih2 | 0pad]  (128 rows padded, invalid rows zero-masked).
// State vector per stream = [h2 (100) | h1 (5) | 0pad] lives in LDS,
// double-buffered; read as uniform float4 broadcasts (conflict-free).
// 2 batch streams per wave give 8 independent pk-FMA chains of ILP.
__global__ __launch_bounds__(64) void rnn_wave(
    const float* __restrict__ x,
    const float* __restrict__ Wih1, const float* __restrict__ Whh1,
    const float* __restrict__ bih1, const float* __restrict__ bhh1,
    const float* __restrict__ Wih2, const float* __restrict__ Whh2,
    const float* __restrict__ bih2, const float* __restrict__ bhh2,
    const float* __restrict__ W3,   const float* __restrict__ b3,
    float* __restrict__ out)
{
    const int bbase = blockIdx.x * NS;
    const int lane  = threadIdx.x;          // 0..63
    const int r0    = lane;                 // always valid (<100)
    const int r1    = lane + 64;            // valid for lanes 0..35
    const bool r1v  = (r1 < H2);
    const float mB  = r1v ? 1.0f : 0.0f;
    const int r1c   = r1v ? r1 : 0;

    __shared__ __align__(16) float xs[NS][T_STEPS];       // 2 KB
    __shared__ __align__(16) float st[2][NS][KROW];       // extended state

    // ---- preload x: NS*256 = 512 floats = 128 float4 ----
    {
        const float4* xg = reinterpret_cast<const float4*>(x + (size_t)bbase * T_STEPS);
        float4* xd = reinterpret_cast<float4*>(&xs[0][0]);
        xd[lane]      = xg[lane];
        xd[lane + 64] = xg[lane + 64];
    }

    // ---- extended weight rows in registers: 54 f32x2 per row ----
    f32x2 wA[2 * NK4], wB[2 * NK4];
    #pragma unroll
    for (int k4 = 0; k4 < H2 / 4; ++k4) {   // Whh2 part (k4 = 0..24)
        float4 va = *reinterpret_cast<const float4*>(Whh2 + r0 * H2 + 4 * k4);
        wA[2 * k4 + 0] = f32x2{va.x, va.y};
        wA[2 * k4 + 1] = f32x2{va.z, va.w};
        float4 vb = *reinterpret_cast<const float4*>(Whh2 + r1c * H2 + 4 * k4);
        wB[2 * k4 + 0] = f32x2{vb.x * mB, vb.y * mB};
        wB[2 * k4 + 1] = f32x2{vb.z * mB, vb.w * mB};
    }
    // Wih2 part (elements 100..104), rest zero (k4 = 25,26)
    wA[50] = f32x2{Wih2[r0 * H1 + 0], Wih2[r0 * H1 + 1]};
    wA[51] = f32x2{Wih2[r0 * H1 + 2], Wih2[r0 * H1 + 3]};
    wA[52] = f32x2{Wih2[r0 * H1 + 4], 0.0f};
    wA[53] = f32x2{0.0f, 0.0f};
    wB[50] = f32x2{Wih2[r1c * H1 + 0] * mB, Wih2[r1c * H1 + 1] * mB};
    wB[51] = f32x2{Wih2[r1c * H1 + 2] * mB, Wih2[r1c * H1 + 3] * mB};
    wB[52] = f32x2{Wih2[r1c * H1 + 4] * mB, 0.0f};
    wB[53] = f32x2{0.0f, 0.0f};

    const float biasA = bih2[r0] + bhh2[r0];
    const float biasB = (bih2[r1c] + bhh2[r1c]) * mB;

    // ---- layer-1 lanes: lane < 10 -> (stream ls, index li) ----
    const bool l1act = (lane < NS * H1);
    const int  ls    = (lane < H1) ? 0 : 1;
    const int  li    = l1act ? (lane - ls * H1) : 0;
    float w1[H1];
    #pragma unroll
    for (int k = 0; k < H1; ++k) w1[k] = Whh1[li * H1 + k];
    const float wi1 = Wih1[li];
    const float b1  = bih1[li] + bhh1[li];

    // ---- zero-init state (2*NS*112 = 448 floats, 7 per lane) ----
    #pragma unroll
    for (int i = 0; i < 7; ++i) (&st[0][0][0])[lane + 64 * i] = 0.0f;
    // h1_0 = tanh(Wih1*x_0 + b1)  (h1_{-1} = 0); intra-wave visibility only.
    if (l1act) st[0][ls][H2 + li] = fast_tanh(wi1 * xs[ls][0] + b1);

    // ---- one recurrence step: reads st[cur], writes st[nxt] ----
    auto step = [&](int cur, int t) {
        const int nxt = cur ^ 1;
        f32x2 a0{biasA, 0.f}, c0{0.f, 0.f};   // stream 0, row r0
        f32x2 a1{biasB, 0.f}, c1{0.f, 0.f};   // stream 0, row r1
        f32x2 a2{biasA, 0.f}, c2{0.f, 0.f};   // stream 1, row r0
        f32x2 a3{biasB, 0.f}, c3{0.f, 0.f};   // stream 1, row r1
        #pragma unroll
        for (int k4 = 0; k4 < NK4; ++k4) {
            const float4 h0 = *reinterpret_cast<const float4*>(&st[cur][0][4 * k4]);
            const float4 h1 = *reinterpret_cast<const float4*>(&st[cur][1][4 * k4]);
            const f32x2 h0lo{h0.x, h0.y}, h0hi{h0.z, h0.w};
            const f32x2 h1lo{h1.x, h1.y}, h1hi{h1.z, h1.w};
            a0 = __builtin_elementwise_fma(wA[2 * k4 + 0], h0lo, a0);
            c0 = __builtin_elementwise_fma(wA[2 * k4 + 1], h0hi, c0);
            a1 = __builtin_elementwise_fma(wB[2 * k4 + 0], h0lo, a1);
            c1 = __builtin_elementwise_fma(wB[2 * k4 + 1], h0hi, c1);
            a2 = __builtin_elementwise_fma(wA[2 * k4 + 0], h1lo, a2);
            c2 = __builtin_elementwise_fma(wA[2 * k4 + 1], h1hi, c2);
            a3 = __builtin_elementwise_fma(wB[2 * k4 + 0], h1lo, a3);
            c3 = __builtin_elementwise_fma(wB[2 * k4 + 1], h1hi, c3);
        }
        const float hnA0 = fast_tanh((a0.x + a0.y) + (c0.x + c0.y));
        const float hnB0 = fast_tanh((a1.x + a1.y) + (c1.x + c1.y));
        const float hnA1 = fast_tanh((a2.x + a2.y) + (c2.x + c2.y));
        const float hnB1 = fast_tanh((a3.x + a3.y) + (c3.x + c3.y));

        // layer-1 recurrence for t+1 (lanes 0..9), h1 lives at st[...][100+k]
        if (l1act && (t + 1 < T_STEPS)) {
            float u = wi1 * xs[ls][t + 1] + b1;
            #pragma unroll
            for (int k = 0; k < H1; ++k) u += w1[k] * st[cur][ls][H2 + k];
            st[nxt][ls][H2 + li] = fast_tanh(u);
        }
        // h2 writes (pads 105..111 stay zero forever)
        st[nxt][0][r0] = hnA0;
        st[nxt][1][r0] = hnA1;
        if (r1v) { st[nxt][0][r1] = hnB0; st[nxt][1][r1] = hnB1; }
    };

    for (int t = 0; t < T_STEPS; t += 2) {   // T even: ends with state in st[0]
        step(0, t);
        step(1, t + 1);
    }

    // ---- epilogue: out[b+s] = relu(W3 · h2_last + b3), wave reduce ----
    const float w3a = W3[r0];
    const float w3b = r1v ? W3[r1] : 0.0f;
    float p0 = w3a * st[0][0][r0] + w3b * st[0][0][r1c];
    float p1 = w3a * st[0][1][r0] + w3b * st[0][1][r1c];
    #pragma unroll
    for (int off = 32; off > 0; off >>= 1) {
        p0 += __shfl_xor(p0, off, 64);
        p1 += __shfl_xor(p1, off, 64);
    }
    if (lane == 0) {
        const float bb = b3[0];
        out[bbase + 0] = fmaxf(p0 + bb, 0.0f);
        out[bbase + 1] = fmaxf(p1 + bb, 0.0f);
    }
}

extern "C" void kernel_launch(void* const* d_in, const int* in_sizes, int n_in,
                              void* d_out, int out_size, void* d_ws, size_t ws_size,
                              hipStream_t stream) {
    const float* x    = (const float*)d_in[0];
    const float* Wih1 = (const float*)d_in[1];
    const float* Whh1 = (const float*)d_in[2];
    const float* bih1 = (const float*)d_in[3];
    const float* bhh1 = (const float*)d_in[4];
    const float* Wih2 = (const float*)d_in[5];
    const float* Whh2 = (const float*)d_in[6];
    const float* bih2 = (const float*)d_in[7];
    const float* bhh2 = (const float*)d_in[8];
    const float* W3   = (const float*)d_in[9];
    const float* b3   = (const float*)d_in[10];
    float* out = (float*)d_out;

    const int B = in_sizes[0] / T_STEPS;   // 4096
    rnn_wave<<<B / NS, 64, 0, stream>>>(x, Wih1, Whh1, bih1, bhh1,
                                        Wih2, Whh2, bih2, bhh2, W3, b3, out);
}

// Round 6
// 731.581 us; speedup vs baseline: 2.7007x; 2.7007x over previous
//
#include <hip/hip_runtime.h>

#define T_STEPS 256
#define H1 5
#define H2 100
#define KROW 108     // extended state: 100 h2 + 5 h1 + 3 zero pad
#define NK4 27       // KROW/4 float4 groups

typedef float f32x2 __attribute__((ext_vector_type(2)));

// tanh(x) = 1 - 2/(exp(2x)+1); saturates correctly for |x| large.
__device__ __forceinline__ float fast_tanh(float v) {
    float e = __expf(2.0f * v);
    return 1.0f - 2.0f * __builtin_amdgcn_rcpf(e + 1.0f);
}

// ONE WAVE PER BLOCK, ONE BATCH PER WAVE — zero __syncthreads, zero barriers.
// Lane l owns rows l and l+64 of the extended weight matrix [Whh2 | Wih2 | 0]
// (rows >= 100 zero-masked). Extended state [h2(100) | h1(5) | 0(3)] is
// double-buffered in LDS, read as uniform float4 broadcasts (conflict-free).
// Weights: 216 VGPRs; total ~250 — fits the 256 arch file, no spill.
__global__ __launch_bounds__(64) void rnn_wave1(
    const float* __restrict__ x,
    const float* __restrict__ Wih1, const float* __restrict__ Whh1,
    const float* __restrict__ bih1, const float* __restrict__ bhh1,
    const float* __restrict__ Wih2, const float* __restrict__ Whh2,
    const float* __restrict__ bih2, const float* __restrict__ bhh2,
    const float* __restrict__ W3,   const float* __restrict__ b3,
    float* __restrict__ out)
{
    const int b    = blockIdx.x;
    const int lane = threadIdx.x;           // 0..63
    const int r0   = lane;                  // rows 0..63 (always valid)
    const int r1   = lane + 64;             // rows 64..127 (valid < 100)
    const bool r1v = (r1 < H2);
    const float mB = r1v ? 1.0f : 0.0f;
    const int r1c  = r1v ? r1 : 0;

    __shared__ __align__(16) float xs[T_STEPS];   // 1 KB
    __shared__ __align__(16) float st[2][KROW];   // double-buffered ext. state

    // ---- preload x row: 256 floats = 64 float4 (one per lane) ----
    reinterpret_cast<float4*>(xs)[lane] =
        reinterpret_cast<const float4*>(x + (size_t)b * T_STEPS)[lane];

    // ---- extended weight rows in registers: 54 f32x2 per row ----
    f32x2 wA[2 * NK4], wB[2 * NK4];
    #pragma unroll
    for (int k4 = 0; k4 < H2 / 4; ++k4) {     // Whh2 part, k4 = 0..24
        float4 va = *reinterpret_cast<const float4*>(Whh2 + r0 * H2 + 4 * k4);
        wA[2 * k4 + 0] = f32x2{va.x, va.y};
        wA[2 * k4 + 1] = f32x2{va.z, va.w};
        float4 vb = *reinterpret_cast<const float4*>(Whh2 + r1c * H2 + 4 * k4);
        wB[2 * k4 + 0] = f32x2{vb.x * mB, vb.y * mB};
        wB[2 * k4 + 1] = f32x2{vb.z * mB, vb.w * mB};
    }
    // Wih2 part (state slots 100..104), zeros at 105..107 (k4 = 25, 26)
    wA[50] = f32x2{Wih2[r0 * H1 + 0], Wih2[r0 * H1 + 1]};
    wA[51] = f32x2{Wih2[r0 * H1 + 2], Wih2[r0 * H1 + 3]};
    wA[52] = f32x2{Wih2[r0 * H1 + 4], 0.0f};
    wA[53] = f32x2{0.0f, 0.0f};
    wB[50] = f32x2{Wih2[r1c * H1 + 0] * mB, Wih2[r1c * H1 + 1] * mB};
    wB[51] = f32x2{Wih2[r1c * H1 + 2] * mB, Wih2[r1c * H1 + 3] * mB};
    wB[52] = f32x2{Wih2[r1c * H1 + 4] * mB, 0.0f};
    wB[53] = f32x2{0.0f, 0.0f};

    const float biasA = bih2[r0] + bhh2[r0];
    const float biasB = (bih2[r1c] + bhh2[r1c]) * mB;

    // ---- layer-1 (lanes 0..4): row li of the 5-dim recurrence ----
    const bool l1act = (lane < H1);
    const int  li    = l1act ? lane : 0;
    float w1[H1];
    #pragma unroll
    for (int k = 0; k < H1; ++k) w1[k] = Whh1[li * H1 + k];
    const float wi1 = Wih1[li];
    const float b1  = bih1[li] + bhh1[li];

    // ---- zero-init state (2*108 = 216 floats) ----
    #pragma unroll
    for (int i = 0; i < 4; ++i) {
        const int idx = lane + 64 * i;
        if (idx < 2 * KROW) (&st[0][0])[idx] = 0.0f;
    }
    // h1_0 = tanh(Wih1*x_0 + b1)  (h1_{-1} = 0); intra-wave visibility only.
    if (l1act) st[0][H2 + li] = fast_tanh(wi1 * xs[0] + b1);

    float* scp = &st[0][0];
    float* snp = &st[1][0];

    #pragma unroll 1
    for (int t = 0; t < T_STEPS; ++t) {
        f32x2 a0{biasA, 0.f}, a1{0.f, 0.f};   // row r0, two chains
        f32x2 b0{biasB, 0.f}, b1a{0.f, 0.f};  // row r1, two chains
        #pragma unroll
        for (int k4 = 0; k4 < NK4; ++k4) {
            const float4 hv = *reinterpret_cast<const float4*>(scp + 4 * k4);
            const f32x2 hlo{hv.x, hv.y}, hhi{hv.z, hv.w};
            a0  = __builtin_elementwise_fma(wA[2 * k4 + 0], hlo, a0);
            a1  = __builtin_elementwise_fma(wA[2 * k4 + 1], hhi, a1);
            b0  = __builtin_elementwise_fma(wB[2 * k4 + 0], hlo, b0);
            b1a = __builtin_elementwise_fma(wB[2 * k4 + 1], hhi, b1a);
        }
        const float hA = fast_tanh((a0.x + a0.y) + (a1.x + a1.y));
        const float hB = fast_tanh((b0.x + b0.y) + (b1a.x + b1a.y));

        // layer-1 recurrence for t+1 (lanes 0..4)
        if (l1act && (t + 1 < T_STEPS)) {
            float u = wi1 * xs[t + 1] + b1;
            #pragma unroll
            for (int k = 0; k < H1; ++k) u += w1[k] * scp[H2 + k];
            snp[H2 + li] = fast_tanh(u);
        }
        snp[r0] = hA;
        if (r1v) snp[r1] = hB;
        float* tmp = scp; scp = snp; snp = tmp;
    }

    // ---- epilogue: out[b] = relu(W3 · h2_last + b3), wave reduce ----
    float p = W3[r0] * scp[r0];
    if (r1v) p += W3[r1] * scp[r1];
    #pragma unroll
    for (int off = 32; off > 0; off >>= 1) p += __shfl_xor(p, off, 64);
    if (lane == 0) out[b] = fmaxf(p + b3[0], 0.0f);
}

extern "C" void kernel_launch(void* const* d_in, const int* in_sizes, int n_in,
                              void* d_out, int out_size, void* d_ws, size_t ws_size,
                              hipStream_t stream) {
    const float* x    = (const float*)d_in[0];
    const float* Wih1 = (const float*)d_in[1];
    const float* Whh1 = (const float*)d_in[2];
    const float* bih1 = (const float*)d_in[3];
    const float* bhh1 = (const float*)d_in[4];
    const float* Wih2 = (const float*)d_in[5];
    const float* Whh2 = (const float*)d_in[6];
    const float* bih2 = (const float*)d_in[7];
    const float* bhh2 = (const float*)d_in[8];
    const float* W3   = (const float*)d_in[9];
    const float* b3   = (const float*)d_in[10];
    float* out = (float*)d_out;

    const int B = in_sizes[0] / T_STEPS;   // 4096
    rnn_wave1<<<B, 64, 0, stream>>>(x, Wih1, Whh1, bih1, bhh1,
                                    Wih2, Whh2, bih2, bhh2, W3, b3, out);
}

// Round 7
// 250.138 us; speedup vs baseline: 7.8988x; 2.9247x over previous
//
#include <hip/hip_runtime.h>
#include <stdint.h>

#define T_STEPS 256
#define H1 5
#define H2 100
#define NSTR 16     // batch streams per block (MFMA N dim)
#define MT 7        // M tiles: 112 rows = 100 h2 + 5 h1 + 7 pad
#define KT 4        // K tiles: 128 cols = 100 h2 + 5 h1 + bias + x + 21 pad
#define ME 112
#define KE 128
#define XPAD 260    // xs row stride (floats): 16B-aligned, conflict-light

typedef _Float16 f16;
typedef _Float16 half8 __attribute__((ext_vector_type(8)));
typedef _Float16 f16x2 __attribute__((ext_vector_type(2)));
typedef float    floatx4 __attribute__((ext_vector_type(4)));
typedef uint32_t u32x4 __attribute__((ext_vector_type(4)));

// tanh(x) = 1 - 2/(exp(2x)+1); saturates correctly for |x| large.
__device__ __forceinline__ float fast_tanh(float v) {
    float e = __expf(2.0f * v);
    return 1.0f - 2.0f * __builtin_amdgcn_rcpf(e + 1.0f);
}

// pack two f32 -> u32 of two f16 (RTE via scalar cvt)
__device__ __forceinline__ uint32_t pkf16(float a, float b) {
    f16x2 v; v.x = (f16)a; v.y = (f16)b;
    return __builtin_bit_cast(uint32_t, v);
}

// One wave (64 threads) per 16 batch streams. The full 2-layer RNN step is a
// single 112x128 fp16 matrix-vector recurrence done with 28 MFMAs per step.
//   A rows 0..99:   [Whh2 | Wih2 | bias2 | 0...]      -> h2_t
//   A rows 100..104:[  0  | Whh1 | bias1 | Wih1 | 0]  -> h1_{t+1}
//   B rows (state): [h2_{t-1} | h1_t | 1 | x_{t+1} | 0...]
// D->B remap stays inside each 4-lane column group (shfl), no barriers in loop.
__global__ __launch_bounds__(64, 1) void rnn_mfma(
    const float* __restrict__ x,
    const float* __restrict__ Wih1, const float* __restrict__ Whh1,
    const float* __restrict__ bih1, const float* __restrict__ bhh1,
    const float* __restrict__ Wih2, const float* __restrict__ Whh2,
    const float* __restrict__ bih2, const float* __restrict__ bhh2,
    const float* __restrict__ W3,   const float* __restrict__ b3,
    float* __restrict__ out)
{
    const int lane  = threadIdx.x;       // 0..63
    const int n     = lane & 15;         // stream / A-row-in-tile / D-col
    const int g     = lane >> 4;         // k-group / D-row-group
    const int bbase = blockIdx.x * NSTR;

    __shared__ __align__(16) f16   Wlds[ME][KE];     // 28 KB extended matrix
    __shared__ __align__(16) float xs[NSTR][XPAD];   // 16.6 KB x rows

    // ---- build extended fp16 matrix in LDS ----
    {   // zero (112*128 f16 = 7168 u32)
        uint32_t* w32 = (uint32_t*)&Wlds[0][0];
        #pragma unroll
        for (int i = 0; i < 112; ++i) w32[lane + 64 * i] = 0u;
    }
    __syncthreads();
    for (int i = lane; i < H2 * H2; i += 64) Wlds[i / H2][i % H2] = (f16)Whh2[i];
    for (int i = lane; i < H2 * H1; i += 64) Wlds[i / H1][H2 + i % H1] = (f16)Wih2[i];
    for (int i = lane; i < H2; i += 64)      Wlds[i][105] = (f16)(bih2[i] + bhh2[i]);
    if (lane < H1 * H1) Wlds[H2 + lane / H1][H2 + lane % H1] = (f16)Whh1[lane];
    if (lane < H1) {
        Wlds[H2 + lane][105] = (f16)(bih1[lane] + bhh1[lane]);
        Wlds[H2 + lane][106] = (f16)Wih1[lane];
    }
    // ---- preload x (16 rows x 256) into padded LDS ----
    {
        const float4* xg = (const float4*)(x + (size_t)bbase * T_STEPS);
        #pragma unroll
        for (int i = 0; i < 16; ++i) {
            const int gi = lane + 64 * i;          // 0..1023 float4s
            const int row = gi >> 6, c4 = gi & 63;
            *(float4*)&xs[row][4 * c4] = xg[gi];
        }
    }
    __syncthreads();

    // ---- A fragments: lane holds A[16mt + n][32kt + 8g + j], j=0..7 ----
    half8 Af[MT][KT];
    #pragma unroll
    for (int mt = 0; mt < MT; ++mt)
        #pragma unroll
        for (int kt = 0; kt < KT; ++kt)
            Af[mt][kt] = *(const half8*)&Wlds[16 * mt + n][32 * kt + 8 * g];

    // ---- initial B: h2_{-1}=0, h1_0, 1, x_1 ----
    half8 Bf[KT];
    #pragma unroll
    for (int kt = 0; kt < KT; ++kt)
        #pragma unroll
        for (int j = 0; j < 8; ++j) Bf[kt][j] = (f16)0.0f;
    {
        const float x0 = xs[n][0];
        if (g == 0) {           // B rows 100..103 = h1_0[0..3]
            #pragma unroll
            for (int c = 0; c < 4; ++c)
                Bf[3][4 + c] = (f16)fast_tanh(Wih1[c] * x0 + bih1[c] + bhh1[c]);
        } else if (g == 1) {    // rows 104 (h1_0[4]), 105 (=1), 106 (=x_1)
            Bf[3][0] = (f16)fast_tanh(Wih1[4] * x0 + bih1[4] + bhh1[4]);
            Bf[3][1] = (f16)1.0f;
            Bf[3][2] = (f16)xs[n][1];
        }
    }

    // D->B remap lane sources (within the 4-lane column group n,n+16,n+32,n+48)
    const int  s0   = n + ((lane & 16) << 1);   // n + 32*(g&1)
    const int  s1   = s0 + 16;
    const bool gLow = (lane < 32);              // g < 2

    uint32_t P0[MT], P1[MT];   // packed f16 state pairs per M-tile

    #pragma unroll 1
    for (int t = 0; t < T_STEPS; ++t) {
        floatx4 D[MT];
        #pragma unroll
        for (int mt = 0; mt < MT; ++mt) { floatx4 z = {0.f, 0.f, 0.f, 0.f}; D[mt] = z; }
        #pragma unroll
        for (int kt = 0; kt < KT; ++kt)
            #pragma unroll
            for (int mt = 0; mt < MT; ++mt)
                D[mt] = __builtin_amdgcn_mfma_f32_16x16x32_f16(Af[mt][kt], Bf[kt], D[mt], 0, 0, 0);

        // tanh + pack: rows 16mt+4g+{0..3}; dead rows (105..111) harmlessly tanh(0)=0
        #pragma unroll
        for (int mt = 0; mt < MT; ++mt) {
            P0[mt] = pkf16(fast_tanh(D[mt][0]), fast_tanh(D[mt][1]));
            P1[mt] = pkf16(fast_tanh(D[mt][2]), fast_tanh(D[mt][3]));
        }
        if (t == T_STEPS - 1) break;

        // ---- build next B: lane(kt,g_B) needs rows 32kt+8g_B+j from
        //      mt = 2kt+(g_B>>1), source groups g_D = 2(g_B&1), +1 ----
        #pragma unroll
        for (int kt = 0; kt < 3; ++kt) {
            const uint32_t aa0 = (uint32_t)__shfl((int)P0[2 * kt],     s0);
            const uint32_t ab0 = (uint32_t)__shfl((int)P0[2 * kt + 1], s0);
            const uint32_t aa1 = (uint32_t)__shfl((int)P1[2 * kt],     s0);
            const uint32_t ab1 = (uint32_t)__shfl((int)P1[2 * kt + 1], s0);
            const uint32_t aa2 = (uint32_t)__shfl((int)P0[2 * kt],     s1);
            const uint32_t ab2 = (uint32_t)__shfl((int)P0[2 * kt + 1], s1);
            const uint32_t aa3 = (uint32_t)__shfl((int)P1[2 * kt],     s1);
            const uint32_t ab3 = (uint32_t)__shfl((int)P1[2 * kt + 1], s1);
            u32x4 r;
            r.x = gLow ? aa0 : ab0;
            r.y = gLow ? aa1 : ab1;
            r.z = gLow ? aa2 : ab2;
            r.w = gLow ? aa3 : ab3;
            Bf[kt] = __builtin_bit_cast(half8, r);
        }
        {   // kt = 3: rows 96..103 (g_B=0) | 104, 1.0, x_{t+2}, 0 (g_B=1) | 0
            const uint32_t a0 = (uint32_t)__shfl((int)P0[6], s0);
            const uint32_t a1 = (uint32_t)__shfl((int)P1[6], s0);
            const uint32_t a2 = (uint32_t)__shfl((int)P0[6], s1);
            const uint32_t a3 = (uint32_t)__shfl((int)P1[6], s1);
            const int xi = (t + 2 < T_STEPS) ? (t + 2) : (T_STEPS - 1);
            const uint32_t xp = pkf16(xs[n][xi], 0.0f);
            u32x4 r;
            r.x = (g == 0) ? a0 : (g == 1) ? ((a0 & 0xffffu) | 0x3C000000u) : 0u;
            r.y = (g == 0) ? a1 : (g == 1) ? xp : 0u;
            r.z = (g == 0) ? a2 : 0u;
            r.w = (g == 0) ? a3 : 0u;
            Bf[3] = __builtin_bit_cast(half8, r);
        }
    }

    // ---- out[n] = relu(W3 . h2_255 + b3): mask rows >= 100, reduce 4-lane group ----
    float p = 0.0f;
    #pragma unroll
    for (int mt = 0; mt < MT; ++mt) {
        const int mbase = 16 * mt + 4 * g;
        float4 w3v = make_float4(0.f, 0.f, 0.f, 0.f);
        if (mbase < H2) w3v = *(const float4*)(W3 + mbase);
        const f16x2 lo = __builtin_bit_cast(f16x2, P0[mt]);
        const f16x2 hi = __builtin_bit_cast(f16x2, P1[mt]);
        p += w3v.x * (float)lo.x + w3v.y * (float)lo.y
           + w3v.z * (float)hi.x + w3v.w * (float)hi.y;
    }
    p += __shfl_xor(p, 16);
    p += __shfl_xor(p, 32);
    if (lane < NSTR) out[bbase + n] = fmaxf(p + b3[0], 0.0f);
}

extern "C" void kernel_launch(void* const* d_in, const int* in_sizes, int n_in,
                              void* d_out, int out_size, void* d_ws, size_t ws_size,
                              hipStream_t stream) {
    const float* x    = (const float*)d_in[0];
    const float* Wih1 = (const float*)d_in[1];
    const float* Whh1 = (const float*)d_in[2];
    const float* bih1 = (const float*)d_in[3];
    const float* bhh1 = (const float*)d_in[4];
    const float* Wih2 = (const float*)d_in[5];
    const float* Whh2 = (const float*)d_in[6];
    const float* bih2 = (const float*)d_in[7];
    const float* bhh2 = (const float*)d_in[8];
    const float* W3   = (const float*)d_in[9];
    const float* b3   = (const float*)d_in[10];
    float* out = (float*)d_out;

    const int B = in_sizes[0] / T_STEPS;   // 4096
    rnn_mfma<<<B / NSTR, 64, 0, stream>>>(x, Wih1, Whh1, bih1, bhh1,
                                          Wih2, Whh2, bih2, bhh2, W3, b3, out);
}

// Round 8
// 227.200 us; speedup vs baseline: 8.6962x; 1.1010x over previous
//
#include <hip/hip_runtime.h>
#include <stdint.h>

#define T_STEPS 256
#define H1 5
#define H2 100
#define NSTR 16     // batch streams per block (MFMA N dim)
#define MT 7        // M tiles: 112 rows = 100 h2 + 5 h1 + 7 pad
#define KT 4        // K tiles: 128 cols = 100 h2 + 5 h1 + bias + x + 21 pad
#define ME 112
#define KE 128
#define SROW 136    // state row stride in f16 (272 B, 16B-aligned)
#define XPAD 260    // xs row stride (floats)

typedef _Float16 f16;
typedef _Float16 half8 __attribute__((ext_vector_type(8)));
typedef _Float16 f16x2 __attribute__((ext_vector_type(2)));
typedef float    floatx4 __attribute__((ext_vector_type(4)));

// tanh(x) = 1 - 2/(exp(2x)+1); saturates correctly for |x| large.
__device__ __forceinline__ float fast_tanh(float v) {
    float e = __expf(2.0f * v);
    return 1.0f - 2.0f * __builtin_amdgcn_rcpf(e + 1.0f);
}

// pack two f32 -> u32 of two f16 (RTE)
__device__ __forceinline__ uint32_t pkf16(float a, float b) {
    f16x2 v; v.x = (f16)a; v.y = (f16)b;
    return __builtin_bit_cast(uint32_t, v);
}

// One wave (64 threads) per 16 batch streams. Full 2-layer RNN step = one
// 112x128 fp16 matrix-vector recurrence, 28 MFMAs per step.
//   A rows 0..99:   [Whh2 | Wih2 | bias2 | 0...]      -> h2_t
//   A rows 100..104:[  0  | Whh1 | bias1 | Wih1 | 0]  -> h1_{t+1}
//   state row n:    [h2 | h1 | 1 | x | 0...]  (f16, LDS, single-buffered)
// D->nextB remap goes through LDS: 7 ds_write_b64 then 4 ds_read_b128.
// Single wave => DS ops are in-order; no barriers in the loop.
__global__ __launch_bounds__(64, 1) void rnn_mfma_lds(
    const float* __restrict__ x,
    const float* __restrict__ Wih1, const float* __restrict__ Whh1,
    const float* __restrict__ bih1, const float* __restrict__ bhh1,
    const float* __restrict__ Wih2, const float* __restrict__ Whh2,
    const float* __restrict__ bih2, const float* __restrict__ bhh2,
    const float* __restrict__ W3,   const float* __restrict__ b3,
    float* __restrict__ out)
{
    const int lane  = threadIdx.x;       // 0..63
    const int n     = lane & 15;         // stream / A-row-in-tile / D-col
    const int g     = lane >> 4;         // k-group / D-row-group
    const int bbase = blockIdx.x * NSTR;

    __shared__ __align__(16) f16   Wlds[ME][KE];     // 28 KB extended matrix
    __shared__ __align__(16) float xs[NSTR][XPAD];   // 16.6 KB x rows
    __shared__ __align__(16) f16   st[NSTR][SROW];   // 4.25 KB state

    // ---- build extended fp16 matrix in LDS ----
    {   // zero (112*128 f16 = 7168 u32)
        uint32_t* w32 = (uint32_t*)&Wlds[0][0];
        #pragma unroll
        for (int i = 0; i < 112; ++i) w32[lane + 64 * i] = 0u;
    }
    __syncthreads();
    for (int i = lane; i < H2 * H2; i += 64) Wlds[i / H2][i % H2] = (f16)Whh2[i];
    for (int i = lane; i < H2 * H1; i += 64) Wlds[i / H1][H2 + i % H1] = (f16)Wih2[i];
    for (int i = lane; i < H2; i += 64)      Wlds[i][105] = (f16)(bih2[i] + bhh2[i]);
    if (lane < H1 * H1) Wlds[H2 + lane / H1][H2 + lane % H1] = (f16)Whh1[lane];
    if (lane < H1) {
        Wlds[H2 + lane][105] = (f16)(bih1[lane] + bhh1[lane]);
        Wlds[H2 + lane][106] = (f16)Wih1[lane];
    }
    // ---- preload x (16 rows x 256) into padded LDS ----
    {
        const float4* xg = (const float4*)(x + (size_t)bbase * T_STEPS);
        #pragma unroll
        for (int i = 0; i < 16; ++i) {
            const int gi = lane + 64 * i;          // 0..1023 float4s
            const int row = gi >> 6, c4 = gi & 63;
            *(float4*)&xs[row][4 * c4] = xg[gi];
        }
    }
    __syncthreads();

    // ---- A fragments: lane holds A[16mt + n][32kt + 8g + j], j=0..7 ----
    half8 Af[MT][KT];
    #pragma unroll
    for (int mt = 0; mt < MT; ++mt)
        #pragma unroll
        for (int kt = 0; kt < KT; ++kt)
            Af[mt][kt] = *(const half8*)&Wlds[16 * mt + n][32 * kt + 8 * g];

    // ---- initial state: [h2=0 | h1_0 | 1 | x_1 | 0...] ----
    {
        uint32_t* s32 = (uint32_t*)&st[0][0];
        for (int i = lane; i < NSTR * SROW / 2; i += 64) s32[i] = 0u;
    }
    if (lane < NSTR) {
        const float x0 = xs[lane][0];
        #pragma unroll
        for (int c = 0; c < H1; ++c)
            st[lane][H2 + c] = (f16)fast_tanh(Wih1[c] * x0 + bih1[c] + bhh1[c]);
        st[lane][105] = (f16)1.0f;
        st[lane][106] = (f16)xs[lane][1];
    }
    __syncthreads();

    char* const strow = (char*)&st[n][0];     // stream n's state row
    uint32_t P0[MT], P1[MT];                  // packed f16 row pairs per M-tile

    #pragma unroll 1
    for (int t = 0; t < T_STEPS; ++t) {
        // B fragments straight from state row (natural MFMA B layout)
        half8 Bf[KT];
        #pragma unroll
        for (int kt = 0; kt < KT; ++kt)
            Bf[kt] = *(const half8*)(strow + 64 * kt + 16 * g);

        floatx4 D[MT];
        #pragma unroll
        for (int mt = 0; mt < MT; ++mt) { floatx4 z = {0.f, 0.f, 0.f, 0.f}; D[mt] = z; }
        #pragma unroll
        for (int kt = 0; kt < KT; ++kt)
            #pragma unroll
            for (int mt = 0; mt < MT; ++mt)
                D[mt] = __builtin_amdgcn_mfma_f32_16x16x32_f16(Af[mt][kt], Bf[kt], D[mt], 0, 0, 0);

        // tanh + pack: lane holds rows 16mt+4g+{0..3}
        #pragma unroll
        for (int mt = 0; mt < 6; ++mt) {
            P0[mt] = pkf16(fast_tanh(D[mt][0]), fast_tanh(D[mt][1]));
            P1[mt] = pkf16(fast_tanh(D[mt][2]), fast_tanh(D[mt][3]));
        }
        // mt=6: rows 96..111. g=0: h2, g=1: h1, g=2: [h1[4], 1.0 | x_{t+2}, 0], g=3: pad
        if (g < 2) {
            P0[6] = pkf16(fast_tanh(D[6][0]), fast_tanh(D[6][1]));
            P1[6] = pkf16(fast_tanh(D[6][2]), fast_tanh(D[6][3]));
        } else if (g == 2) {
            const int xi = (t + 2 < T_STEPS) ? (t + 2) : (T_STEPS - 1);
            P0[6] = pkf16(fast_tanh(D[6][0]), 1.0f);
            P1[6] = pkf16(xs[n][xi], 0.0f);
        } else {
            P0[6] = 0u; P1[6] = 0u;
        }

        if (t == T_STEPS - 1) break;   // keep final state in P regs

        // write rows 16mt+4g+0..3 back to the state row: 7 x ds_write_b64
        #pragma unroll
        for (int mt = 0; mt < MT; ++mt) {
            uint2 w; w.x = P0[mt]; w.y = P1[mt];
            *(uint2*)(strow + 32 * mt + 8 * g) = w;
        }
    }

    // ---- out[n] = relu(W3 . h2_255 + b3): mask rows >= 100, reduce groups ----
    float p = 0.0f;
    #pragma unroll
    for (int mt = 0; mt < MT; ++mt) {
        const int mbase = 16 * mt + 4 * g;
        float4 w3v = make_float4(0.f, 0.f, 0.f, 0.f);
        if (mbase < H2) w3v = *(const float4*)(W3 + mbase);
        const f16x2 lo = __builtin_bit_cast(f16x2, P0[mt]);
        const f16x2 hi = __builtin_bit_cast(f16x2, P1[mt]);
        p += w3v.x * (float)lo.x + w3v.y * (float)lo.y
           + w3v.z * (float)hi.x + w3v.w * (float)hi.y;
    }
    p += __shfl_xor(p, 16);
    p += __shfl_xor(p, 32);
    if (lane < NSTR) out[bbase + n] = fmaxf(p + b3[0], 0.0f);
}

extern "C" void kernel_launch(void* const* d_in, const int* in_sizes, int n_in,
                              void* d_out, int out_size, void* d_ws, size_t ws_size,
                              hipStream_t stream) {
    const float* x    = (const float*)d_in[0];
    const float* Wih1 = (const float*)d_in[1];
    const float* Whh1 = (const float*)d_in[2];
    const float* bih1 = (const float*)d_in[3];
    const float* bhh1 = (const float*)d_in[4];
    const float* Wih2 = (const float*)d_in[5];
    const float* Whh2 = (const float*)d_in[6];
    const float* bih2 = (const float*)d_in[7];
    const float* bhh2 = (const float*)d_in[8];
    const float* W3   = (const float*)d_in[9];
    const float* b3   = (const float*)d_in[10];
    float* out = (float*)d_out;

    const int B = in_sizes[0] / T_STEPS;   // 4096
    rnn_mfma_lds<<<B / NSTR, 64, 0, stream>>>(x, Wih1, Whh1, bih1, bhh1,
                                              Wih2, Whh2, bih2, bhh2, W3, b3, out);
}

// Round 9
// 117.539 us; speedup vs baseline: 16.8096x; 1.9330x over previous
//
#include <hip/hip_runtime.h>
#include <stdint.h>

#define T_STEPS 256
#define H1 5
#define H2 100
#define NSTR 16     // batch streams per block (MFMA N dim)
#define MT 7        // M tiles: 112 rows = 100 h2 + 5 h1 + 7 pad
#define KT 4        // K tiles: 128 cols = 100 h2 + 5 h1 + bias + x + 21 pad
#define ME 112
#define KE 128
#define SROW 136    // state row stride in f16 (272 B, 16B-aligned)
#define XPAD 260    // xs row stride (floats)
#define NW 4        // waves per block (M-split)

typedef _Float16 f16;
typedef _Float16 half8 __attribute__((ext_vector_type(8)));
typedef _Float16 f16x2 __attribute__((ext_vector_type(2)));
typedef float    floatx4 __attribute__((ext_vector_type(4)));

// tanh(x) = 1 - 2/(exp(2x)+1); saturates correctly for |x| large.
__device__ __forceinline__ float fast_tanh(float v) {
    float e = __expf(2.0f * v);
    return 1.0f - 2.0f * __builtin_amdgcn_rcpf(e + 1.0f);
}

// pack two f32 -> u32 of two f16 (RTE)
__device__ __forceinline__ uint32_t pkf16(float a, float b) {
    f16x2 v; v.x = (f16)a; v.y = (f16)b;
    return __builtin_bit_cast(uint32_t, v);
}

// 4 waves per block, 16 batch streams per block. Full 2-layer RNN step = one
// 112x128 fp16 matrix-vector recurrence; the 7 M-tiles are split across the
// 4 waves (2+2+2+1) so all 4 SIMDs of the CU work on the same stream group.
//   A rows 0..99:   [Whh2 | Wih2 | bias2 | 0...]      -> h2_t
//   A rows 100..104:[  0  | Whh1 | bias1 | Wih1 | 0]  -> h1_{t+1}
//   state row n:    [h2 | h1 | 1 | x | 0...]  (f16, LDS, double-buffered)
// One __syncthreads per step: read st[cur] -> MFMA -> tanh -> write st[nxt].
__global__ __launch_bounds__(256, 1) void rnn_mfma4(
    const float* __restrict__ x,
    const float* __restrict__ Wih1, const float* __restrict__ Whh1,
    const float* __restrict__ bih1, const float* __restrict__ bhh1,
    const float* __restrict__ Wih2, const float* __restrict__ Whh2,
    const float* __restrict__ bih2, const float* __restrict__ bhh2,
    const float* __restrict__ W3,   const float* __restrict__ b3,
    float* __restrict__ out)
{
    const int tid  = threadIdx.x;        // 0..255
    const int lane = tid & 63;
    const int wid  = tid >> 6;           // wave id: M-tile group
    const int n    = lane & 15;          // stream / D-col
    const int g    = lane >> 4;          // k-group / D-row-group
    const int bbase = blockIdx.x * NSTR;
    const int mt0   = 2 * wid;           // this wave's first M-tile

    __shared__ __align__(16) f16   Wlds[ME][KE];       // 28 KB extended matrix
    __shared__ __align__(16) float xs[NSTR][XPAD];     // 16.6 KB x rows
    __shared__ __align__(16) f16   st[2][NSTR][SROW];  // 8.7 KB state (dbuf)
    __shared__ float pp[NW][NSTR];                     // epilogue partials

    // ---- zero Wlds (7168 u32) + preload x (1024 float4) ----
    {
        uint32_t* w32 = (uint32_t*)&Wlds[0][0];
        #pragma unroll
        for (int i = 0; i < (ME * KE / 2) / 256; ++i) w32[tid + 256 * i] = 0u;
        const float4* xg = (const float4*)(x + (size_t)bbase * T_STEPS);
        #pragma unroll
        for (int i = 0; i < 4; ++i) {
            const int gi = tid + 256 * i;            // 0..1023
            *(float4*)&xs[gi >> 6][4 * (gi & 63)] = xg[gi];
        }
    }
    __syncthreads();
    // ---- fill extended matrix + zero state ----
    for (int i = tid; i < H2 * H2; i += 256) Wlds[i / H2][i % H2] = (f16)Whh2[i];
    for (int i = tid; i < H2 * H1; i += 256) Wlds[i / H1][H2 + i % H1] = (f16)Wih2[i];
    for (int i = tid; i < H2; i += 256)      Wlds[i][105] = (f16)(bih2[i] + bhh2[i]);
    if (tid < H1 * H1) Wlds[H2 + tid / H1][H2 + tid % H1] = (f16)Whh1[tid];
    if (tid < H1) {
        Wlds[H2 + tid][105] = (f16)(bih1[tid] + bhh1[tid]);
        Wlds[H2 + tid][106] = (f16)Wih1[tid];
    }
    {
        uint32_t* s32 = (uint32_t*)&st[0][0][0];
        for (int i = tid; i < 2 * NSTR * SROW / 2; i += 256) s32[i] = 0u;
    }
    __syncthreads();
    // ---- initial state: [h2=0 | h1_0 | 1 | x_1 | 0...] ----
    if (tid < NSTR) {
        const float x0 = xs[tid][0];
        #pragma unroll
        for (int c = 0; c < H1; ++c)
            st[0][tid][H2 + c] = (f16)fast_tanh(Wih1[c] * x0 + bih1[c] + bhh1[c]);
        st[0][tid][105] = (f16)1.0f;
        st[0][tid][106] = (f16)xs[tid][1];
    }
    // ---- A fragments for this wave's tiles (wave 3: tile 1 is zero dummy) ----
    half8 Af[2][KT];
    #pragma unroll
    for (int i = 0; i < 2; ++i) {
        if (mt0 + i < MT) {
            #pragma unroll
            for (int kt = 0; kt < KT; ++kt)
                Af[i][kt] = *(const half8*)&Wlds[16 * (mt0 + i) + n][32 * kt + 8 * g];
        } else {
            #pragma unroll
            for (int kt = 0; kt < KT; ++kt) {
                half8 z = {0, 0, 0, 0, 0, 0, 0, 0};
                Af[i][kt] = z;
            }
        }
    }
    __syncthreads();

    const char* scur = (const char*)&st[0][n][0];
    char*       snxt = (char*)&st[1][n][0];
    uint32_t P0[2], P1[2];

    #pragma unroll 1
    for (int t = 0; t < T_STEPS; ++t) {
        half8 Bf[KT];
        #pragma unroll
        for (int kt = 0; kt < KT; ++kt)
            Bf[kt] = *(const half8*)(scur + 64 * kt + 16 * g);

        floatx4 D[2];
        #pragma unroll
        for (int i = 0; i < 2; ++i) { floatx4 z = {0.f, 0.f, 0.f, 0.f}; D[i] = z; }
        #pragma unroll
        for (int kt = 0; kt < KT; ++kt)
            #pragma unroll
            for (int i = 0; i < 2; ++i)
                D[i] = __builtin_amdgcn_mfma_f32_16x16x32_f16(Af[i][kt], Bf[kt], D[i], 0, 0, 0);

        // tanh + pack: lane holds rows 16(mt0+i) + 4g + {0..3}
        #pragma unroll
        for (int i = 0; i < 2; ++i) {
            P0[i] = pkf16(fast_tanh(D[i][0]), fast_tanh(D[i][1]));
            P1[i] = pkf16(fast_tanh(D[i][2]), fast_tanh(D[i][3]));
        }
        if (wid == 3) {   // mt6 rows 96..111: g2 -> [h1[4], 1 | x_{t+2}, 0]; g3 pad
            if (g == 2) {
                const int xi = (t + 2 < T_STEPS) ? (t + 2) : (T_STEPS - 1);
                P0[0] = pkf16(fast_tanh(D[0][0]), 1.0f);
                P1[0] = pkf16(xs[n][xi], 0.0f);
            } else if (g == 3) { P0[0] = 0u; P1[0] = 0u; }
            P0[1] = 0u; P1[1] = 0u;      // pad cols 112..127 stay zero
        }

        if (t == T_STEPS - 1) break;     // uniform exit; final state in P regs

        #pragma unroll
        for (int i = 0; i < 2; ++i) {
            uint2 w; w.x = P0[i]; w.y = P1[i];
            *(uint2*)(snxt + 32 * (mt0 + i) + 8 * g) = w;
        }
        __syncthreads();
        char* tmp = (char*)scur; scur = (const char*)snxt; snxt = tmp;
    }

    // ---- epilogue: out[n] = relu(W3 . h2_255 + b3) ----
    float p = 0.0f;
    #pragma unroll
    for (int i = 0; i < 2; ++i) {
        const int mbase = 16 * (mt0 + i) + 4 * g;
        if (mbase < H2) {
            const float4 w3v = *(const float4*)(W3 + mbase);
            const f16x2 lo = __builtin_bit_cast(f16x2, P0[i]);
            const f16x2 hi = __builtin_bit_cast(f16x2, P1[i]);
            p += w3v.x * (float)lo.x + w3v.y * (float)lo.y
               + w3v.z * (float)hi.x + w3v.w * (float)hi.y;
        }
    }
    p += __shfl_xor(p, 16);
    p += __shfl_xor(p, 32);
    if (lane < NSTR) pp[wid][n] = p;
    __syncthreads();
    if (tid < NSTR)
        out[bbase + tid] = fmaxf(pp[0][tid] + pp[1][tid] + pp[2][tid] + pp[3][tid]
                                 + b3[0], 0.0f);
}

extern "C" void kernel_launch(void* const* d_in, const int* in_sizes, int n_in,
                              void* d_out, int out_size, void* d_ws, size_t ws_size,
                              hipStream_t stream) {
    const float* x    = (const float*)d_in[0];
    const float* Wih1 = (const float*)d_in[1];
    const float* Whh1 = (const float*)d_in[2];
    const float* bih1 = (const float*)d_in[3];
    const float* bhh1 = (const float*)d_in[4];
    const float* Wih2 = (const float*)d_in[5];
    const float* Whh2 = (const float*)d_in[6];
    const float* bih2 = (const float*)d_in[7];
    const float* bhh2 = (const float*)d_in[8];
    const float* W3   = (const float*)d_in[9];
    const float* b3   = (const float*)d_in[10];
    float* out = (float*)d_out;

    const int B = in_sizes[0] / T_STEPS;   // 4096
    rnn_mfma4<<<B / NSTR, NW * 64, 0, stream>>>(x, Wih1, Whh1, bih1, bhh1,
                                                Wih2, Whh2, bih2, bhh2, W3, b3, out);
}

// Round 10
// 100.401 us; speedup vs baseline: 19.6790x; 1.1707x over previous
//
#include <hip/hip_runtime.h>
#include <stdint.h>

#define T_STEPS 256
#define H1 5
#define H2 100
#define NSTR 16     // batch streams per block (MFMA N dim)
#define MT 7        // M tiles: 112 rows = 100 h2 + 5 h1 + 7 pad
#define KT 4        // K tiles: 128 cols = 100 h2 + 5 h1 + bias + x + 21 pad
#define ME 112
#define KE 128
#define SROW 136    // state row stride in f16 (272 B, 16B-aligned)
#define XPAD 260    // xs row stride (floats)
#define NW 7        // waves per block: one M-tile per wave
#define NTHR (NW * 64)

typedef _Float16 f16;
typedef _Float16 half8 __attribute__((ext_vector_type(8)));
typedef _Float16 f16x2 __attribute__((ext_vector_type(2)));
typedef float    floatx4 __attribute__((ext_vector_type(4)));

// tanh(x) = 1 - 2/(exp(2x)+1); saturates correctly for |x| large.
__device__ __forceinline__ float fast_tanh(float v) {
    float e = __expf(2.0f * v);
    return 1.0f - 2.0f * __builtin_amdgcn_rcpf(e + 1.0f);
}

// pack two f32 -> u32 of two f16 (RTE)
__device__ __forceinline__ uint32_t pkf16(float a, float b) {
    f16x2 v; v.x = (f16)a; v.y = (f16)b;
    return __builtin_bit_cast(uint32_t, v);
}

// 7 waves per block, 16 batch streams, one 16-row M-tile per wave.
// Full 2-layer RNN step = one 112x128 fp16 matrix-vector recurrence:
//   A rows 0..99:   [Whh2 | Wih2 | bias2 | 0...]      -> h2_t
//   A rows 100..104:[  0  | Whh1 | bias1 | Wih1 | 0]  -> h1_{t+1}
//   state row n:    [h2 | h1 | 1 | x | 0...]  (f16, LDS, double-buffered)
// Per wave-step: 4 ds_read_b128 (B) -> 4 MFMA -> 4 tanh -> 1 ds_write_b64,
// one __syncthreads per step. Minimizes the serial chain per step.
__global__ __launch_bounds__(NTHR, 1) void rnn_mfma7(
    const float* __restrict__ x,
    const float* __restrict__ Wih1, const float* __restrict__ Whh1,
    const float* __restrict__ bih1, const float* __restrict__ bhh1,
    const float* __restrict__ Wih2, const float* __restrict__ Whh2,
    const float* __restrict__ bih2, const float* __restrict__ bhh2,
    const float* __restrict__ W3,   const float* __restrict__ b3,
    float* __restrict__ out)
{
    const int tid  = threadIdx.x;        // 0..447
    const int lane = tid & 63;
    const int wid  = tid >> 6;           // wave id == M-tile id
    const int n    = lane & 15;          // stream / D-col
    const int g    = lane >> 4;          // k-group / D-row-group
    const int bbase = blockIdx.x * NSTR;

    __shared__ __align__(16) f16   Wlds[ME][KE];       // 28 KB extended matrix
    __shared__ __align__(16) float xs[NSTR][XPAD];     // 16.6 KB x rows
    __shared__ __align__(16) f16   st[2][NSTR][SROW];  // 8.7 KB state (dbuf)
    __shared__ float pp[NW][NSTR];                     // epilogue partials

    // ---- zero Wlds (7168 u32 = 448*16) + preload x (1024 float4) ----
    {
        uint32_t* w32 = (uint32_t*)&Wlds[0][0];
        #pragma unroll
        for (int i = 0; i < 16; ++i) w32[tid + NTHR * i] = 0u;
        const float4* xg = (const float4*)(x + (size_t)bbase * T_STEPS);
        for (int gi = tid; gi < 1024; gi += NTHR)
            *(float4*)&xs[gi >> 6][4 * (gi & 63)] = xg[gi];
    }
    __syncthreads();
    // ---- fill extended matrix + zero state ----
    for (int i = tid; i < H2 * H2; i += NTHR) Wlds[i / H2][i % H2] = (f16)Whh2[i];
    for (int i = tid; i < H2 * H1; i += NTHR) Wlds[i / H1][H2 + i % H1] = (f16)Wih2[i];
    for (int i = tid; i < H2; i += NTHR)      Wlds[i][105] = (f16)(bih2[i] + bhh2[i]);
    if (tid < H1 * H1) Wlds[H2 + tid / H1][H2 + tid % H1] = (f16)Whh1[tid];
    if (tid < H1) {
        Wlds[H2 + tid][105] = (f16)(bih1[tid] + bhh1[tid]);
        Wlds[H2 + tid][106] = (f16)Wih1[tid];
    }
    {
        uint32_t* s32 = (uint32_t*)&st[0][0][0];
        for (int i = tid; i < 2 * NSTR * SROW / 2; i += NTHR) s32[i] = 0u;
    }
    __syncthreads();
    // ---- initial state: [h2=0 | h1_0 | 1 | x_1 | 0...] ----
    if (tid < NSTR) {
        const float x0 = xs[tid][0];
        #pragma unroll
        for (int c = 0; c < H1; ++c)
            st[0][tid][H2 + c] = (f16)fast_tanh(Wih1[c] * x0 + bih1[c] + bhh1[c]);
        st[0][tid][105] = (f16)1.0f;
        st[0][tid][106] = (f16)xs[tid][1];
    }
    // ---- A fragments for this wave's tile ----
    half8 Af[KT];
    #pragma unroll
    for (int kt = 0; kt < KT; ++kt)
        Af[kt] = *(const half8*)&Wlds[16 * wid + n][32 * kt + 8 * g];
    __syncthreads();

    const char* scur = (const char*)&st[0][n][0];
    char*       snxt = (char*)&st[1][n][0];
    uint32_t P0, P1;

    #pragma unroll 1
    for (int t = 0; t < T_STEPS; ++t) {
        half8 Bf[KT];
        #pragma unroll
        for (int kt = 0; kt < KT; ++kt)
            Bf[kt] = *(const half8*)(scur + 64 * kt + 16 * g);

        // x for injection (wave 6 only; overlaps with MFMA chain)
        float xv = 0.0f;
        if (wid == 6) {
            const int xi = (t + 2 < T_STEPS) ? (t + 2) : (T_STEPS - 1);
            xv = xs[n][xi];
        }

        floatx4 D = {0.f, 0.f, 0.f, 0.f};
        #pragma unroll
        for (int kt = 0; kt < KT; ++kt)
            D = __builtin_amdgcn_mfma_f32_16x16x32_f16(Af[kt], Bf[kt], D, 0, 0, 0);

        // tanh + pack: lane holds rows 16*wid + 4g + {0..3}
        P0 = pkf16(fast_tanh(D[0]), fast_tanh(D[1]));
        P1 = pkf16(fast_tanh(D[2]), fast_tanh(D[3]));
        if (wid == 6) {   // rows 96..111: g2 -> [h1[4], 1 | x_{t+2}, 0]; g3 pad
            if (g == 2) {
                P0 = pkf16(fast_tanh(D[0]), 1.0f);
                P1 = pkf16(xv, 0.0f);
            } else if (g == 3) { P0 = 0u; P1 = 0u; }
        }

        if (t == T_STEPS - 1) break;     // uniform exit; final state in P regs

        uint2 w; w.x = P0; w.y = P1;
        *(uint2*)(snxt + 32 * wid + 8 * g) = w;
        __syncthreads();
        char* tmp = (char*)scur; scur = (const char*)snxt; snxt = tmp;
    }

    // ---- epilogue: out[n] = relu(W3 . h2_255 + b3) ----
    float p = 0.0f;
    {
        const int mbase = 16 * wid + 4 * g;
        if (mbase < H2) {
            const float4 w3v = *(const float4*)(W3 + mbase);
            const f16x2 lo = __builtin_bit_cast(f16x2, P0);
            const f16x2 hi = __builtin_bit_cast(f16x2, P1);
            p += w3v.x * (float)lo.x + w3v.y * (float)lo.y
               + w3v.z * (float)hi.x + w3v.w * (float)hi.y;
        }
    }
    p += __shfl_xor(p, 16);
    p += __shfl_xor(p, 32);
    if (lane < NSTR) pp[wid][n] = p;
    __syncthreads();
    if (tid < NSTR) {
        float s = b3[0];
        #pragma unroll
        for (int w = 0; w < NW; ++w) s += pp[w][tid];
        out[bbase + tid] = fmaxf(s, 0.0f);
    }
}

extern "C" void kernel_launch(void* const* d_in, const int* in_sizes, int n_in,
                              void* d_out, int out_size, void* d_ws, size_t ws_size,
                              hipStream_t stream) {
    const float* x    = (const float*)d_in[0];
    const float* Wih1 = (const float*)d_in[1];
    const float* Whh1 = (const float*)d_in[2];
    const float* bih1 = (const float*)d_in[3];
    const float* bhh1 = (const float*)d_in[4];
    const float* Wih2 = (const float*)d_in[5];
    const float* Whh2 = (const float*)d_in[6];
    const float* bih2 = (const float*)d_in[7];
    const float* bhh2 = (const float*)d_in[8];
    const float* W3   = (const float*)d_in[9];
    const float* b3   = (const float*)d_in[10];
    float* out = (float*)d_out;

    const int B = in_sizes[0] / T_STEPS;   // 4096
    rnn_mfma7<<<B / NSTR, NTHR, 0, stream>>>(x, Wih1, Whh1, bih1, bhh1,
                                             Wih2, Whh2, bih2, bhh2, W3, b3, out);
}

// Round 11
// 97.602 us; speedup vs baseline: 20.2433x; 1.0287x over previous
//
#include <hip/hip_runtime.h>
#include <stdint.h>

#define T_STEPS 256
#define H1 5
#define H2 100
#define NSTR 16     // batch streams per block (MFMA N dim)
#define MT 7        // M tiles: 112 rows = 100 h2 + 5 h1 + 7 pad
#define KT 4        // K tiles: 128 cols = 100 h2 + 5 h1 + bias + x + 21 pad
#define ME 112
#define KE 128
#define XPAD 260    // xs row stride (floats)
#define NW 7        // waves per block: one M-tile per wave
#define NTHR (NW * 64)

typedef _Float16 f16;
typedef _Float16 half8 __attribute__((ext_vector_type(8)));
typedef _Float16 f16x2 __attribute__((ext_vector_type(2)));
typedef float    floatx4 __attribute__((ext_vector_type(4)));

// State buffer layout (per buffer, 2048 f16 = 4 KB):
//   16B chunk (kt, g, n) at byte offset kt*1024 + g*256 + n*16
//   holds k-rows 32kt+8g .. +7 of stream n.
// B-read for lane l=(g*16+n): addr = lane*16 + kt*1024  -> perfectly linear.
// f16 index of (k, n): ((k>>5)<<9) + (((k>>3)&3)<<7) + (n<<3) + (k&7)
__device__ __forceinline__ int sidx(int k, int n) {
    return ((k >> 5) << 9) + (((k >> 3) & 3) << 7) + (n << 3) + (k & 7);
}

// tanh(x) = 1 - 2/(exp(2x)+1); saturates correctly for |x| large.
__device__ __forceinline__ float fast_tanh(float v) {
    float e = __expf(2.0f * v);
    return 1.0f - 2.0f * __builtin_amdgcn_rcpf(e + 1.0f);
}

// pack two f32 -> u32 of two f16 (RTE)
__device__ __forceinline__ uint32_t pkf16(float a, float b) {
    f16x2 v; v.x = (f16)a; v.y = (f16)b;
    return __builtin_bit_cast(uint32_t, v);
}

// 7 waves per block, 16 batch streams, one 16-row M-tile per wave.
// Full 2-layer RNN step = one 112x128 fp16 matrix-vector recurrence:
//   A rows 0..99:   [Whh2 | Wih2 | bias2 | 0...]      -> h2_t
//   A rows 100..104:[  0  | Whh1 | bias1 | Wih1 | 0]  -> h1_{t+1}
// State double-buffered in LDS in B-fragment order (see sidx) so the per-step
// reads are linear and the writes tile all 32 banks. One barrier per step.
__global__ __launch_bounds__(NTHR, 1) void rnn_mfma7s(
    const float* __restrict__ x,
    const float* __restrict__ Wih1, const float* __restrict__ Whh1,
    const float* __restrict__ bih1, const float* __restrict__ bhh1,
    const float* __restrict__ Wih2, const float* __restrict__ Whh2,
    const float* __restrict__ bih2, const float* __restrict__ bhh2,
    const float* __restrict__ W3,   const float* __restrict__ b3,
    float* __restrict__ out)
{
    const int tid  = threadIdx.x;        // 0..447
    const int lane = tid & 63;
    const int wid  = tid >> 6;           // wave id == M-tile id
    const int n    = lane & 15;          // stream / D-col
    const int g    = lane >> 4;          // k-group / D-row-group
    const int bbase = blockIdx.x * NSTR;

    __shared__ __align__(16) f16   Wlds[ME][KE];     // 28 KB extended matrix
    __shared__ __align__(16) float xs[NSTR][XPAD];   // 16.6 KB x rows
    __shared__ __align__(16) f16   st[2][2048];      // 8 KB state (dbuf)
    __shared__ float pp[NW][NSTR];                   // epilogue partials

    // ---- zero Wlds (7168 u32 = 448*16) + preload x (1024 float4) ----
    {
        uint32_t* w32 = (uint32_t*)&Wlds[0][0];
        #pragma unroll
        for (int i = 0; i < 16; ++i) w32[tid + NTHR * i] = 0u;
        const float4* xg = (const float4*)(x + (size_t)bbase * T_STEPS);
        for (int gi = tid; gi < 1024; gi += NTHR)
            *(float4*)&xs[gi >> 6][4 * (gi & 63)] = xg[gi];
    }
    __syncthreads();
    // ---- fill extended matrix + zero state ----
    for (int i = tid; i < H2 * H2; i += NTHR) Wlds[i / H2][i % H2] = (f16)Whh2[i];
    for (int i = tid; i < H2 * H1; i += NTHR) Wlds[i / H1][H2 + i % H1] = (f16)Wih2[i];
    for (int i = tid; i < H2; i += NTHR)      Wlds[i][105] = (f16)(bih2[i] + bhh2[i]);
    if (tid < H1 * H1) Wlds[H2 + tid / H1][H2 + tid % H1] = (f16)Whh1[tid];
    if (tid < H1) {
        Wlds[H2 + tid][105] = (f16)(bih1[tid] + bhh1[tid]);
        Wlds[H2 + tid][106] = (f16)Wih1[tid];
    }
    {
        uint32_t* s32 = (uint32_t*)&st[0][0];
        for (int i = tid; i < 2 * 2048 / 2; i += NTHR) s32[i] = 0u;
    }
    __syncthreads();
    // ---- initial state: h2=0, h1_0 at k=100..104, 1 at k=105, x_1 at k=106 ----
    if (tid < NSTR) {
        const float x0 = xs[tid][0];
        #pragma unroll
        for (int c = 0; c < H1; ++c)
            st[0][sidx(H2 + c, tid)] = (f16)fast_tanh(Wih1[c] * x0 + bih1[c] + bhh1[c]);
        st[0][sidx(105, tid)] = (f16)1.0f;
        st[0][sidx(106, tid)] = (f16)xs[tid][1];
    }
    // ---- A fragments for this wave's tile ----
    half8 Af[KT];
    #pragma unroll
    for (int kt = 0; kt < KT; ++kt)
        Af[kt] = *(const half8*)&Wlds[16 * wid + n][32 * kt + 8 * g];
    __syncthreads();

    // read base: linear per lane; write slot: D rows 16wid+4g+{0..3}, col n
    const int roff = 16 * lane;
    const int woff = ((wid >> 1) << 10) + (((2 * wid + (g >> 1)) & 3) << 8)
                   + (n << 4) + ((g & 1) << 3);
    const char* scur = (const char*)&st[0][0];
    char*       snxt = (char*)&st[1][0];
    uint32_t P0, P1;

    #pragma unroll 1
    for (int t = 0; t < T_STEPS; ++t) {
        half8 Bf[KT];
        #pragma unroll
        for (int kt = 0; kt < KT; ++kt)
            Bf[kt] = *(const half8*)(scur + roff + 1024 * kt);

        // x for injection (wave 6 only; overlaps with MFMA chain)
        float xv = 0.0f;
        if (wid == 6) {
            const int xi = (t + 2 < T_STEPS) ? (t + 2) : (T_STEPS - 1);
            xv = xs[n][xi];
        }

        floatx4 D = {0.f, 0.f, 0.f, 0.f};
        #pragma unroll
        for (int kt = 0; kt < KT; ++kt)
            D = __builtin_amdgcn_mfma_f32_16x16x32_f16(Af[kt], Bf[kt], D, 0, 0, 0);

        // tanh + pack: lane holds rows 16*wid + 4g + {0..3}, col n
        P0 = pkf16(fast_tanh(D[0]), fast_tanh(D[1]));
        P1 = pkf16(fast_tanh(D[2]), fast_tanh(D[3]));
        if (wid == 6) {   // rows 104..107 (g2): [h1[4], 1 | x_{t+2}, 0]; g3: pad
            if (g == 2) {
                P0 = pkf16(fast_tanh(D[0]), 1.0f);
                P1 = pkf16(xv, 0.0f);
            } else if (g == 3) { P0 = 0u; P1 = 0u; }
        }

        if (t == T_STEPS - 1) break;     // uniform exit; final state in P regs

        uint2 w; w.x = P0; w.y = P1;
        *(uint2*)(snxt + woff) = w;
        __syncthreads();
        char* tmp = (char*)scur; scur = (const char*)snxt; snxt = tmp;
    }

    // ---- epilogue: out[n] = relu(W3 . h2_255 + b3) ----
    float p = 0.0f;
    {
        const int mbase = 16 * wid + 4 * g;
        if (mbase < H2) {
            const float4 w3v = *(const float4*)(W3 + mbase);
            const f16x2 lo = __builtin_bit_cast(f16x2, P0);
            const f16x2 hi = __builtin_bit_cast(f16x2, P1);
            p += w3v.x * (float)lo.x + w3v.y * (float)lo.y
               + w3v.z * (float)hi.x + w3v.w * (float)hi.y;
        }
    }
    p += __shfl_xor(p, 16);
    p += __shfl_xor(p, 32);
    if (lane < NSTR) pp[wid][n] = p;
    __syncthreads();
    if (tid < NSTR) {
        float s = b3[0];
        #pragma unroll
        for (int w = 0; w < NW; ++w) s += pp[w][tid];
        out[bbase + tid] = fmaxf(s, 0.0f);
    }
}

extern "C" void kernel_launch(void* const* d_in, const int* in_sizes, int n_in,
                              void* d_out, int out_size, void* d_ws, size_t ws_size,
                              hipStream_t stream) {
    const float* x    = (const float*)d_in[0];
    const float* Wih1 = (const float*)d_in[1];
    const float* Whh1 = (const float*)d_in[2];
    const float* bih1 = (const float*)d_in[3];
    const float* bhh1 = (const float*)d_in[4];
    const float* Wih2 = (const float*)d_in[5];
    const float* Whh2 = (const float*)d_in[6];
    const float* bih2 = (const float*)d_in[7];
    const float* bhh2 = (const float*)d_in[8];
    const float* W3   = (const float*)d_in[9];
    const float* b3   = (const float*)d_in[10];
    float* out = (float*)d_out;

    const int B = in_sizes[0] / T_STEPS;   // 4096
    rnn_mfma7s<<<B / NSTR, NTHR, 0, stream>>>(x, Wih1, Whh1, bih1, bhh1,
                                              Wih2, Whh2, bih2, bhh2, W3, b3, out);
}

// Round 12
// 96.808 us; speedup vs baseline: 20.4093x; 1.0082x over previous
//
#include <hip/hip_runtime.h>
#include <stdint.h>

#define T_STEPS 256
#define H1 5
#define H2 100
#define NSTR 16     // batch streams per block (MFMA N dim)
#define MT 7        // M tiles: 112 rows = 100 h2 + 5 h1 + 7 pad
#define KT 4        // K tiles: 128 cols = 100 h2 + 5 h1 + bias + x + 21 pad
#define ME 112
#define KE 128
#define XPAD 260    // xs row stride (floats)
#define NW 7        // waves per block: one M-tile per wave
#define NTHR (NW * 64)

typedef _Float16 f16;
typedef _Float16 half8 __attribute__((ext_vector_type(8)));
typedef _Float16 f16x2 __attribute__((ext_vector_type(2)));
typedef float    floatx4 __attribute__((ext_vector_type(4)));

// State buffer layout (per buffer, 2048 f16 = 4 KB):
//   16B chunk (kt, g, n) at byte offset kt*1024 + g*256 + n*16
//   holds k-rows 32kt+8g .. +7 of stream n.
// B-read for lane l=(g*16+n): addr = lane*16 + kt*1024  -> perfectly linear.
// f16 index of (k, n): ((k>>5)<<9) + (((k>>3)&3)<<7) + (n<<3) + (k&7)
__device__ __forceinline__ int sidx(int k, int n) {
    return ((k >> 5) << 9) + (((k >> 3) & 3) << 7) + (n << 3) + (k & 7);
}

// tanh(x) = 1 - 2/(exp(2x)+1); saturates correctly for |x| large.
__device__ __forceinline__ float fast_tanh(float v) {
    float e = __expf(2.0f * v);
    return 1.0f - 2.0f * __builtin_amdgcn_rcpf(e + 1.0f);
}

// pack two f32 -> u32 of two f16 (RTE)
__device__ __forceinline__ uint32_t pkf16(float a, float b) {
    f16x2 v; v.x = (f16)a; v.y = (f16)b;
    return __builtin_bit_cast(uint32_t, v);
}

// 7 waves per block, 16 batch streams, one 16-row M-tile per wave.
// Full 2-layer RNN step = one 112x128 fp16 matrix-vector recurrence:
//   A rows 0..99:   [Whh2 | Wih2 | bias2 | 0...]      -> h2_t
//   A rows 100..104:[  0  | Whh1 | bias1 | Wih1 | 0]  -> h1_{t+1}
// State double-buffered in LDS in B-fragment order (sidx): linear reads,
// bank-tiled writes. One barrier per step. This round: 2 independent MFMA
// accumulation chains, t-loop unrolled x2 (explicit ping/pong), setprio(1)
// around the compute phase.
__global__ __launch_bounds__(NTHR, 1) void rnn_mfma7p(
    const float* __restrict__ x,
    const float* __restrict__ Wih1, const float* __restrict__ Whh1,
    const float* __restrict__ bih1, const float* __restrict__ bhh1,
    const float* __restrict__ Wih2, const float* __restrict__ Whh2,
    const float* __restrict__ bih2, const float* __restrict__ bhh2,
    const float* __restrict__ W3,   const float* __restrict__ b3,
    float* __restrict__ out)
{
    const int tid  = threadIdx.x;        // 0..447
    const int lane = tid & 63;
    const int wid  = tid >> 6;           // wave id == M-tile id
    const int n    = lane & 15;          // stream / D-col
    const int g    = lane >> 4;          // k-group / D-row-group
    const int bbase = blockIdx.x * NSTR;

    __shared__ __align__(16) f16   Wlds[ME][KE];     // 28 KB extended matrix
    __shared__ __align__(16) float xs[NSTR][XPAD];   // 16.6 KB x rows
    __shared__ __align__(16) f16   st[2][2048];      // 8 KB state (dbuf)
    __shared__ float pp[NW][NSTR];                   // epilogue partials

    // ---- zero Wlds (7168 u32 = 448*16) + preload x (1024 float4) ----
    {
        uint32_t* w32 = (uint32_t*)&Wlds[0][0];
        #pragma unroll
        for (int i = 0; i < 16; ++i) w32[tid + NTHR * i] = 0u;
        const float4* xg = (const float4*)(x + (size_t)bbase * T_STEPS);
        for (int gi = tid; gi < 1024; gi += NTHR)
            *(float4*)&xs[gi >> 6][4 * (gi & 63)] = xg[gi];
    }
    __syncthreads();
    // ---- fill extended matrix + zero state ----
    for (int i = tid; i < H2 * H2; i += NTHR) Wlds[i / H2][i % H2] = (f16)Whh2[i];
    for (int i = tid; i < H2 * H1; i += NTHR) Wlds[i / H1][H2 + i % H1] = (f16)Wih2[i];
    for (int i = tid; i < H2; i += NTHR)      Wlds[i][105] = (f16)(bih2[i] + bhh2[i]);
    if (tid < H1 * H1) Wlds[H2 + tid / H1][H2 + tid % H1] = (f16)Whh1[tid];
    if (tid < H1) {
        Wlds[H2 + tid][105] = (f16)(bih1[tid] + bhh1[tid]);
        Wlds[H2 + tid][106] = (f16)Wih1[tid];
    }
    {
        uint32_t* s32 = (uint32_t*)&st[0][0];
        for (int i = tid; i < 2 * 2048 / 2; i += NTHR) s32[i] = 0u;
    }
    __syncthreads();
    // ---- initial state: h2=0, h1_0 at k=100..104, 1 at k=105, x_1 at k=106 ----
    if (tid < NSTR) {
        const float x0 = xs[tid][0];
        #pragma unroll
        for (int c = 0; c < H1; ++c)
            st[0][sidx(H2 + c, tid)] = (f16)fast_tanh(Wih1[c] * x0 + bih1[c] + bhh1[c]);
        st[0][sidx(105, tid)] = (f16)1.0f;
        st[0][sidx(106, tid)] = (f16)xs[tid][1];
    }
    // ---- A fragments for this wave's tile ----
    half8 Af[KT];
    #pragma unroll
    for (int kt = 0; kt < KT; ++kt)
        Af[kt] = *(const half8*)&Wlds[16 * wid + n][32 * kt + 8 * g];
    __syncthreads();

    // read base: linear per lane; write slot: D rows 16wid+4g+{0..3}, col n
    const int roff = 16 * lane;
    const int woff = ((wid >> 1) << 10) + (((2 * wid + (g >> 1)) & 3) << 8)
                   + (n << 4) + ((g & 1) << 3);
    const char* const sp0 = (const char*)&st[0][0];
    char*       const sp1 = (char*)&st[1][0];

    // One full recurrence step: read rp, compute, write wp, barrier.
    auto fullstep = [&](const char* rp, char* wp, int t) {
        // x for injection (wave 6 only) — issued before the B burst
        float xv = 0.0f;
        if (wid == 6) {
            const int xi = (t + 2 < T_STEPS) ? (t + 2) : (T_STEPS - 1);
            xv = xs[n][xi];
        }
        half8 Bf[KT];
        #pragma unroll
        for (int kt = 0; kt < KT; ++kt)
            Bf[kt] = *(const half8*)(rp + roff + 1024 * kt);

        __builtin_amdgcn_s_setprio(1);
        floatx4 Da = {0.f, 0.f, 0.f, 0.f}, Db = {0.f, 0.f, 0.f, 0.f};
        Da = __builtin_amdgcn_mfma_f32_16x16x32_f16(Af[0], Bf[0], Da, 0, 0, 0);
        Db = __builtin_amdgcn_mfma_f32_16x16x32_f16(Af[2], Bf[2], Db, 0, 0, 0);
        Da = __builtin_amdgcn_mfma_f32_16x16x32_f16(Af[1], Bf[1], Da, 0, 0, 0);
        Db = __builtin_amdgcn_mfma_f32_16x16x32_f16(Af[3], Bf[3], Db, 0, 0, 0);
        const floatx4 D = Da + Db;

        uint32_t q0 = pkf16(fast_tanh(D[0]), fast_tanh(D[1]));
        uint32_t q1 = pkf16(fast_tanh(D[2]), fast_tanh(D[3]));
        if (wid == 6) {   // rows 104..107 (g2): [h1[4], 1 | x_{t+2}, 0]; g3: pad
            if (g == 2) {
                q0 = pkf16(fast_tanh(D[0]), 1.0f);
                q1 = pkf16(xv, 0.0f);
            } else if (g == 3) { q0 = 0u; q1 = 0u; }
        }
        __builtin_amdgcn_s_setprio(0);

        uint2 w; w.x = q0; w.y = q1;
        *(uint2*)(wp + woff) = w;
        __syncthreads();
    };

    #pragma unroll 1
    for (int t2 = 0; t2 < T_STEPS - 2; t2 += 2) {
        fullstep(sp0, sp1, t2);          // even step: st0 -> st1
        fullstep(sp1, (char*)sp0, t2 + 1);  // odd step: st1 -> st0
    }
    fullstep(sp0, sp1, T_STEPS - 2);     // t = 254: st0 -> st1

    // ---- final step t = 255: compute only, keep P in registers ----
    uint32_t P0, P1;
    {
        half8 Bf[KT];
        #pragma unroll
        for (int kt = 0; kt < KT; ++kt)
            Bf[kt] = *(const half8*)(sp1 + roff + 1024 * kt);
        floatx4 Da = {0.f, 0.f, 0.f, 0.f}, Db = {0.f, 0.f, 0.f, 0.f};
        Da = __builtin_amdgcn_mfma_f32_16x16x32_f16(Af[0], Bf[0], Da, 0, 0, 0);
        Db = __builtin_amdgcn_mfma_f32_16x16x32_f16(Af[2], Bf[2], Db, 0, 0, 0);
        Da = __builtin_amdgcn_mfma_f32_16x16x32_f16(Af[1], Bf[1], Da, 0, 0, 0);
        Db = __builtin_amdgcn_mfma_f32_16x16x32_f16(Af[3], Bf[3], Db, 0, 0, 0);
        const floatx4 D = Da + Db;
        P0 = pkf16(fast_tanh(D[0]), fast_tanh(D[1]));
        P1 = pkf16(fast_tanh(D[2]), fast_tanh(D[3]));
    }

    // ---- epilogue: out[n] = relu(W3 . h2_255 + b3) ----
    float p = 0.0f;
    {
        const int mbase = 16 * wid + 4 * g;
        if (mbase < H2) {
            const float4 w3v = *(const float4*)(W3 + mbase);
            const f16x2 lo = __builtin_bit_cast(f16x2, P0);
            const f16x2 hi = __builtin_bit_cast(f16x2, P1);
            p += w3v.x * (float)lo.x + w3v.y * (float)lo.y
               + w3v.z * (float)hi.x + w3v.w * (float)hi.y;
        }
    }
    p += __shfl_xor(p, 16);
    p += __shfl_xor(p, 32);
    if (lane < NSTR) pp[wid][n] = p;
    __syncthreads();
    if (tid < NSTR) {
        float s = b3[0];
        #pragma unroll
        for (int w = 0; w < NW; ++w) s += pp[w][tid];
        out[bbase + tid] = fmaxf(s, 0.0f);
    }
}

extern "C" void kernel_launch(void* const* d_in, const int* in_sizes, int n_in,
                              void* d_out, int out_size, void* d_ws, size_t ws_size,
                              hipStream_t stream) {
    const float* x    = (const float*)d_in[0];
    const float* Wih1 = (const float*)d_in[1];
    const float* Whh1 = (const float*)d_in[2];
    const float* bih1 = (const float*)d_in[3];
    const float* bhh1 = (const float*)d_in[4];
    const float* Wih2 = (const float*)d_in[5];
    const float* Whh2 = (const float*)d_in[6];
    const float* bih2 = (const float*)d_in[7];
    const float* bhh2 = (const float*)d_in[8];
    const float* W3   = (const float*)d_in[9];
    const float* b3   = (const float*)d_in[10];
    float* out = (float*)d_out;

    const int B = in_sizes[0] / T_STEPS;   // 4096
    rnn_mfma7p<<<B / NSTR, NTHR, 0, stream>>>(x, Wih1, Whh1, bih1, bhh1,
                                              Wih2, Whh2, bih2, bhh2, W3, b3, out);
}